// Round 5
// baseline (405.361 us; speedup 1.0000x reference)
//
#include <hip/hip_runtime.h>

typedef unsigned short u16;
typedef unsigned int   u32;
typedef unsigned long long u64;
typedef short bf16x8 __attribute__((ext_vector_type(8)));
typedef float f32x4  __attribute__((ext_vector_type(4)));
typedef float f32x16 __attribute__((ext_vector_type(16)));

#define NB  32
#define NQ  1024
#define GS  1024
#define NH  8
#define SCQ (0.25f * 1.4426950408889634f)   /* 1/sqrt(16) * log2(e) */
#define MBIG (-1.0e30f)

#define MFMA16(a, b, c) __builtin_amdgcn_mfma_f32_16x16x32_bf16(a, b, c, 0, 0, 0)
#define MFMA32(a, b, c) __builtin_amdgcn_mfma_f32_32x32x16_bf16(a, b, c, 0, 0, 0)

__device__ __forceinline__ u16 f2bf(float f) {  // RNE float->bf16 bits
    u32 u = __float_as_uint(f);
    return (u16)((u + 0x7fffu + ((u >> 16) & 1u)) >> 16);
}
// packed round-half-up: result = bf(a) | bf(b)<<16, 3 VALU ops via v_perm_b32
__device__ __forceinline__ u32 pk2bf(float a, float b) {
    u32 ua = __float_as_uint(a) + 0x8000u;
    u32 ub = __float_as_uint(b) + 0x8000u;
    return __builtin_amdgcn_perm(ub, ua, 0x07060302u);  // bytes [b3 b2 a3 a2]
}

// ---------------------------------------------------------------------------
// MFMA GEMM: C[128x128] = A[128x128] * W^T, K=128 staged once.
// 256 thr = 4 waves; A fp32 -> bf16 in staging.
// W read RAW ([8][128][16] fp32) and converted inline during staging
// (wprep kernel deleted). Epilogue via LDS -> all global stores int4.
// MODE 0: bf16 out row-major.
// MODE 2: bf16 out transposed per batch with slot permutation sigma per
//         16-token group: tbp = tb ^ 12 when (tb>>2 ^ tb>>3)&1 — places key
//         rows so flash's in-register P words feed PV's MFMA32 B operand
//         with NO cross-lane exchange.
// ---------------------------------------------------------------------------
template <int MODE>
__device__ __forceinline__ void mgemm(const float* __restrict__ Ain,
                                      const float* __restrict__ Wraw,
                                      float wsc,
                                      u16* __restrict__ outb,
                                      u16* As, u16* Ws, int row0) {
    const int t    = threadIdx.x;
    const int wv   = t >> 6;
    const int lane = t & 63;
    const int quad = lane >> 4;
    const int c    = lane & 15;

#pragma unroll
    for (int g0 = 0; g0 < 2048; g0 += 256) {
        int g = g0 + t;
        int row = g >> 4, k0 = (g & 15) * 8;
        const float4* ap = (const float4*)&Ain[(size_t)(row0 + row) * 128 + k0];
        float4 a0 = ap[0], a1 = ap[1];
        int4 pk;
        pk.x = (int)pk2bf(a0.x, a0.y);
        pk.y = (int)pk2bf(a0.z, a0.w);
        pk.z = (int)pk2bf(a1.x, a1.y);
        pk.w = (int)pk2bf(a1.z, a1.w);
        *(int4*)&As[row * 136 + k0] = pk;
    }
    // W: Ws[col*136 + k] = bf16(W[h][k][e]*wsc), col = 16h+e.
    // thread-iter: hk = h*128+k (coalesced float8 read), half selects e-octet.
#pragma unroll
    for (int g0 = 0; g0 < 2048; g0 += 256) {
        int idx  = g0 + t;
        int hk   = idx >> 1, half = idx & 1;
        int k    = hk & 127;
        int col0 = (hk >> 7) * 16 + half * 8;
        const float4* wp = (const float4*)&Wraw[hk * 16 + half * 8];
        float4 w0 = wp[0], w1 = wp[1];
        Ws[(col0 + 0) * 136 + k] = f2bf(w0.x * wsc);
        Ws[(col0 + 1) * 136 + k] = f2bf(w0.y * wsc);
        Ws[(col0 + 2) * 136 + k] = f2bf(w0.z * wsc);
        Ws[(col0 + 3) * 136 + k] = f2bf(w0.w * wsc);
        Ws[(col0 + 4) * 136 + k] = f2bf(w1.x * wsc);
        Ws[(col0 + 5) * 136 + k] = f2bf(w1.y * wsc);
        Ws[(col0 + 6) * 136 + k] = f2bf(w1.z * wsc);
        Ws[(col0 + 7) * 136 + k] = f2bf(w1.w * wsc);
    }
    __syncthreads();

    const f32x4 zf = {0.f, 0.f, 0.f, 0.f};
    f32x4 acc[2][8];
#pragma unroll
    for (int s = 0; s < 2; ++s)
#pragma unroll
        for (int j = 0; j < 8; ++j) acc[s][j] = zf;

#pragma unroll
    for (int kt = 0; kt < 4; ++kt) {
        bf16x8 af0 = *(const bf16x8*)&As[(wv * 32 + c) * 136 + kt * 32 + quad * 8];
        bf16x8 af1 = *(const bf16x8*)&As[(wv * 32 + 16 + c) * 136 + kt * 32 + quad * 8];
#pragma unroll
        for (int j = 0; j < 8; ++j) {
            bf16x8 bfr = *(const bf16x8*)&Ws[(j * 16 + c) * 136 + kt * 32 + quad * 8];
            acc[0][j] = MFMA16(af0, bfr, acc[0][j]);
            acc[1][j] = MFMA16(af1, bfr, acc[1][j]);
        }
    }

    // ---- epilogue via LDS: scatter bf16 into As, then coalesced int4 out ----
    __syncthreads();
    u16* Os = As;
#pragma unroll
    for (int s = 0; s < 2; ++s)
#pragma unroll
        for (int j = 0; j < 8; ++j)
#pragma unroll
            for (int r = 0; r < 4; ++r) {
                int lrow = wv * 32 + s * 16 + quad * 4 + r;
                int col  = j * 16 + c;
                u16 v = f2bf(acc[s][j][r]);
                if (MODE == 0) {
                    Os[lrow * 136 + col] = v;
                } else {
                    int u   = lrow & 15;
                    int sw  = ((u >> 2) ^ (u >> 3)) & 1;     // sigma: swap quads 1<->2
                    int tbp = lrow ^ (sw ? 12 : 0);
                    Os[col * 136 + tbp] = v;
                }
            }
    __syncthreads();

    if (MODE == 0) {
#pragma unroll
        for (int it = 0; it < 8; ++it) {
            int chunk = it * 256 + t;
            int lrow = chunk >> 4, c0 = (chunk & 15) * 8;
            *(int4*)&outb[(size_t)(row0 + lrow) * 128 + c0] =
                *(const int4*)&Os[lrow * 136 + c0];
        }
    } else {
        int bI = row0 >> 10, tb0 = row0 & 1023;
#pragma unroll
        for (int it = 0; it < 8; ++it) {
            int chunk = it * 256 + t;
            int col = chunk >> 4, t0 = (chunk & 15) * 8;
            *(int4*)&outb[(size_t)bI * (128 * 1024) + (size_t)col * 1024 + tb0 + t0] =
                *(const int4*)&Os[col * 136 + t0];
        }
    }
}

__global__ __launch_bounds__(256, 2) void proj_mfma(const float* __restrict__ q,
                                                    const float* __restrict__ h,
                                                    const float* __restrict__ Wq,
                                                    const float* __restrict__ Wk,
                                                    const float* __restrict__ Wv,
                                                    const float* __restrict__ Wout,
                                                    u16* __restrict__ Qb,
                                                    u16* __restrict__ Kb,
                                                    u16* __restrict__ Vtg,
                                                    u16* __restrict__ Wob) {
    __shared__ u16 As[128 * 136];
    __shared__ u16 Ws[128 * 136];
    int y = blockIdx.y;
    if (y == 3) {
        // Wob prep: [d][he] = Wout[he>>4][he&15][d], 64 blocks x 256 thr
        if (blockIdx.x < 64) {
            int i = blockIdx.x * 256 + threadIdx.x;    // 0..16383
            int d = i >> 7, he = i & 127;
            Wob[i] = f2bf(Wout[(he >> 4) * 2048 + (he & 15) * 128 + d]);
        }
        return;
    }
    int row0 = blockIdx.x * 128;
    if (y == 0)      mgemm<0>(q, Wq, SCQ,  Qb,  As, Ws, row0);
    else if (y == 1) mgemm<0>(h, Wk, 1.0f, Kb,  As, Ws, row0);
    else             mgemm<2>(h, Wv, 1.0f, Vtg, As, Ws, row0);
}

// ---------------------------------------------------------------------------
// MFMA flash attention + fused out-projection, v5: barrier-free main loop.
// Block = (batch, 32 q-rows), 512 thr = 8 waves = 8 heads; waves free-run.
//  - K score-frag + V^T PV-frag are DIRECT prefetched global loads (L2-hot;
//    same-batch blocks share an XCD under the (b fastest) grid mapping).
//  - Scores: D[key][q] = MFMA32(kf, qf, c) with mask addend in C built from
//    bit-packed mask words: c[r] = sext(bit)&bits(-1e30) -> exp2 underflows
//    masked lanes to exactly 0 (same numerics as v4).
//  - PV: O^T[dim][q] += MFMA32(vf, p, O); p formed IN-REGISTER from exp
//    results (pk2bf pairs). V key rows arrive sigma-permuted from proj so
//    the e-register order IS the B-operand order. A rows 16-31 duplicate
//    rows 0-15 (garbage D rows 16-31 never read).
//  - Mask pre-packed once per block via __ballot into LDS (4 KB).
//  - LDS 13056 B; zero syncthreads between tiles.
// ---------------------------------------------------------------------------
__global__ __launch_bounds__(512, 4) void flash_mfma(const u16* __restrict__ Qb,
                                                     const u16* __restrict__ Kb,
                                                     const u16* __restrict__ Vtg,
                                                     const int* __restrict__ mask,
                                                     const u16* __restrict__ Wob,
                                                     float* __restrict__ out) {
    __shared__ u64 Mb[32][17];          // [q-row][64-key word], pad 17
    __shared__ u16 Hs[32 * 136];

    const int b    = blockIdx.x;
    const int q0   = blockIdx.y * 32;
    const int t    = threadIdx.x;
    const int hh   = t >> 6;
    const int lane = t & 63;
    const int quad = lane >> 4;
    const int c    = lane & 15;
    const int qq   = lane & 31;
    const int hi   = lane >> 5;

    // ---- mask pre-pack: wave hh handles q-rows hh*4..hh*4+3 ----
#pragma unroll
    for (int rr = 0; rr < 4; ++rr) {
        int row = hh * 4 + rr;
        const int* mp = &mask[((size_t)b * NQ + q0 + row) * GS + lane];
#pragma unroll
        for (int jj = 0; jj < 16; ++jj) {
            u64 bal = __ballot(mp[jj * 64] != 0);
            if (lane == 0) Mb[row][jj] = bal;
        }
    }

    bf16x8 qf = *(const bf16x8*)&Qb[((size_t)b * NQ + q0 + qq) * 128 +
                                    hh * 16 + hi * 8];

    const u16* Kp = &Kb[((size_t)b * GS + qq) * 128 + hh * 16 + hi * 8];
    const u16* Vp = &Vtg[(size_t)b * (128 * 1024) + (size_t)(hh * 16 + c) * 1024 +
                         hi * 8];

    bf16x8 kc0 = *(const bf16x8*)(Kp);
    bf16x8 kc1 = *(const bf16x8*)(Kp + 32 * 128);
    bf16x8 vc0 = *(const bf16x8*)(Vp);
    bf16x8 vc1 = *(const bf16x8*)(Vp + 16);
    bf16x8 vc2 = *(const bf16x8*)(Vp + 32);
    bf16x8 vc3 = *(const bf16x8*)(Vp + 48);

    f32x16 O32;
#pragma unroll
    for (int r = 0; r < 16; ++r) O32[r] = 0.f;
    float lsum = 0.f;
    const u32 mbb = __float_as_uint(MBIG);

    __syncthreads();                    // Mb ready
    u64 mw = Mb[qq][0];

    for (int g0 = 0; g0 < GS; g0 += 64) {
        // mask addend C operands from bit word (keys: (r&3)+8*(r>>2)+4hi [+32])
        u32 wlo = ((u32)mw) >> (4 * hi);
        u32 whi = ((u32)(mw >> 32)) >> (4 * hi);
        f32x16 c0, c1;
#pragma unroll
        for (int r = 0; r < 16; ++r) {
            const int pos = (r & 3) + 8 * (r >> 2);
            c0[r] = __uint_as_float(((u32)(((int)(wlo << (31 - pos))) >> 31)) & mbb);
            c1[r] = __uint_as_float(((u32)(((int)(whi << (31 - pos))) >> 31)) & mbb);
        }
        f32x16 s0 = MFMA32(kc0, qf, c0);
        f32x16 s1 = MFMA32(kc1, qf, c1);

        // prefetch next tile (kc/vc consumed above; regs recycle)
        bf16x8 kn0 = kc0, kn1 = kc1, vn0 = vc0, vn1 = vc1, vn2 = vc2, vn3 = vc3;
        u64 mwn = mw;
        if (g0 + 64 < GS) {
            Kp += 64 * 128;
            Vp += 64;
            kn0 = *(const bf16x8*)(Kp);
            kn1 = *(const bf16x8*)(Kp + 32 * 128);
            vn0 = *(const bf16x8*)(Vp);
            vn1 = *(const bf16x8*)(Vp + 16);
            vn2 = *(const bf16x8*)(Vp + 32);
            vn3 = *(const bf16x8*)(Vp + 48);
            mwn = Mb[qq][(g0 >> 6) + 1];
        }

        // chunk 0: exp -> lsum -> pack -> PV (keys 0..31)
#pragma unroll
        for (int r = 0; r < 16; ++r) s0[r] = __builtin_amdgcn_exp2f(s0[r]);
        lsum += ((s0[0] + s0[1]) + (s0[2] + s0[3])) + ((s0[4] + s0[5]) + (s0[6] + s0[7])) +
                (((s0[8] + s0[9]) + (s0[10] + s0[11])) + ((s0[12] + s0[13]) + (s0[14] + s0[15])));
        {
            int4 pa, pb;
            pa.x = (int)pk2bf(s0[0],  s0[1]);  pa.y = (int)pk2bf(s0[2],  s0[3]);
            pa.z = (int)pk2bf(s0[4],  s0[5]);  pa.w = (int)pk2bf(s0[6],  s0[7]);
            pb.x = (int)pk2bf(s0[8],  s0[9]);  pb.y = (int)pk2bf(s0[10], s0[11]);
            pb.z = (int)pk2bf(s0[12], s0[13]); pb.w = (int)pk2bf(s0[14], s0[15]);
            bf16x8 p0, p1;
            __builtin_memcpy(&p0, &pa, 16);
            __builtin_memcpy(&p1, &pb, 16);
            O32 = MFMA32(vc0, p0, O32);
            O32 = MFMA32(vc1, p1, O32);
        }

        // chunk 1: keys 32..63
#pragma unroll
        for (int r = 0; r < 16; ++r) s1[r] = __builtin_amdgcn_exp2f(s1[r]);
        lsum += ((s1[0] + s1[1]) + (s1[2] + s1[3])) + ((s1[4] + s1[5]) + (s1[6] + s1[7])) +
                (((s1[8] + s1[9]) + (s1[10] + s1[11])) + ((s1[12] + s1[13]) + (s1[14] + s1[15])));
        {
            int4 pa, pb;
            pa.x = (int)pk2bf(s1[0],  s1[1]);  pa.y = (int)pk2bf(s1[2],  s1[3]);
            pa.z = (int)pk2bf(s1[4],  s1[5]);  pa.w = (int)pk2bf(s1[6],  s1[7]);
            pb.x = (int)pk2bf(s1[8],  s1[9]);  pb.y = (int)pk2bf(s1[10], s1[11]);
            pb.z = (int)pk2bf(s1[12], s1[13]); pb.w = (int)pk2bf(s1[14], s1[15]);
            bf16x8 p2, p3;
            __builtin_memcpy(&p2, &pa, 16);
            __builtin_memcpy(&p3, &pb, 16);
            O32 = MFMA32(vc2, p2, O32);
            O32 = MFMA32(vc3, p3, O32);
        }

        kc0 = kn0; kc1 = kn1;
        vc0 = vn0; vc1 = vn1; vc2 = vn2; vc3 = vn3;
        mw  = mwn;
    }

    // per-lane q-row denominator: combine hi halves
    lsum += __shfl_xor(lsum, 32);
    float rl = (lsum > 0.f) ? 1.f / lsum : 0.f;

    // O32 reg r (r<8) holds O^T[dim][q=qq]: dims r<4: 4hi+r ; r>=4: 8+4hi+(r-4)
    u32 h0 = pk2bf(O32[0] * rl, O32[1] * rl);
    u32 h1 = pk2bf(O32[2] * rl, O32[3] * rl);
    u32 h2 = pk2bf(O32[4] * rl, O32[5] * rl);
    u32 h3 = pk2bf(O32[6] * rl, O32[7] * rl);
    int2 ha; ha.x = (int)h0; ha.y = (int)h1;
    int2 hb; hb.x = (int)h2; hb.y = (int)h3;
    *(int2*)&Hs[qq * 136 + hh * 16 + 4 * hi]     = ha;
    *(int2*)&Hs[qq * 136 + hh * 16 + 8 + 4 * hi] = hb;
    __syncthreads();

    // fused out-projection: wave hh computes out cols hh*16..+15
    const f32x4 zf = {0.f, 0.f, 0.f, 0.f};
    f32x4 oacc[2] = {zf, zf};
#pragma unroll
    for (int kt = 0; kt < 4; ++kt) {
        bf16x8 bfr = *(const bf16x8*)&Wob[(hh * 16 + c) * 128 + kt * 32 + quad * 8];
#pragma unroll
        for (int s = 0; s < 2; ++s) {
            bf16x8 af = *(const bf16x8*)&Hs[(s * 16 + c) * 136 + kt * 32 + quad * 8];
            oacc[s] = MFMA16(af, bfr, oacc[s]);
        }
    }
#pragma unroll
    for (int s = 0; s < 2; ++s)
#pragma unroll
        for (int r = 0; r < 4; ++r)
            out[((size_t)b * NQ + q0 + s * 16 + quad * 4 + r) * 128 + hh * 16 + c] =
                oacc[s][r];
}

extern "C" void kernel_launch(void* const* d_in, const int* in_sizes, int n_in,
                              void* d_out, int out_size, void* d_ws, size_t ws_size,
                              hipStream_t stream) {
    const float* q    = (const float*)d_in[0];
    const float* h    = (const float*)d_in[1];
    const int*   mask = (const int*)d_in[2];
    const float* Wq   = (const float*)d_in[3];
    const float* Wk   = (const float*)d_in[4];
    const float* Wv   = (const float*)d_in[5];
    const float* Wout = (const float*)d_in[6];
    float* out = (float*)d_out;

    const size_t NTOK = (size_t)NB * NQ;     // 32768
    u16* Qb  = (u16*)d_ws;                   // 8 MB each
    u16* Kb  = Qb + NTOK * 128;
    u16* Vtg = Kb + NTOK * 128;              // V^T per batch, sigma-permuted slots
    u16* Wob = Vtg + NTOK * 128;             // prepped Wout, 32 KB

    proj_mfma<<<dim3(256, 4), 256, 0, stream>>>(q, h, Wq, Wk, Wv, Wout,
                                                Qb, Kb, Vtg, Wob);
    flash_mfma<<<dim3(NB, NQ / 32), 512, 0, stream>>>(Qb, Kb, Vtg, mask,
                                                      Wob, out);
}